// Round 4
// baseline (877.785 us; speedup 1.0000x reference)
//
#include <hip/hip_runtime.h>

#define NN 16000   // nodes
#define NE 64000   // edges
#define HD 90      // hidden
#define NG 512     // graphs

typedef float f32x4 __attribute__((ext_vector_type(4)));
typedef short s16x8 __attribute__((ext_vector_type(8)));

// round-half-up f32 -> bf16
__device__ __forceinline__ unsigned short rhu1(float f) {
  return (unsigned short)((__builtin_bit_cast(unsigned int, f) + 0x8000u) >> 16);
}
__device__ __forceinline__ float bfhi(unsigned int u) {   // high half as f32
  return __builtin_bit_cast(float, u & 0xFFFF0000u);
}
__device__ __forceinline__ float bflo(unsigned int u) {   // low half as f32
  return __builtin_bit_cast(float, u << 16);
}

// h0 = concat(x, pos) : [NN, 16]
__global__ void concat_kernel(const float* __restrict__ x, const float* __restrict__ pos,
                              float* __restrict__ h0) {
  int idx = blockIdx.x * 256 + threadIdx.x;
  if (idx >= NN * 16) return;
  int n = idx >> 4, c = idx & 15;
  h0[idx] = (c < 13) ? x[n * 13 + c] : pos[n * 3 + (c - 13)];
}

// he_bf[e][k] : [NE, 96] bf16. k<90: relu(edge MLP); k==90: 1.0 (bias row); k>90: 0
__global__ void edge_mlp_bf(const float* __restrict__ ea, const float* __restrict__ w1,
                            const float* __restrict__ b1, unsigned short* __restrict__ he) {
  int idx = blockIdx.x * 256 + threadIdx.x;
  if (idx >= NE * 96) return;
  int e = idx / 96, k = idx - e * 96;
  unsigned short v;
  if (k < 90) {
    const float* a = ea + e * 8;
    float acc = b1[k];
#pragma unroll
    for (int j = 0; j < 8; j++) acc = fmaf(a[j], w1[j * HD + k], acc);
    v = rhu1(fmaxf(acc, 0.f));
  } else {
    v = (k == 90) ? (unsigned short)0x3F80 : (unsigned short)0;  // bf16(1.0) / 0
  }
  he[idx] = v;
}

// W' prep: [i][chunk c(3)][o(OCP)][40] bf16; (i,c,o,kk): hk=c*32+kk (kk<32);
// val = hk<90 ? w2[hk][i*OC+o] : hk==90 ? b2[i*OC+o] : 0
__global__ void wprep_kernel(const float* __restrict__ w2, const float* __restrict__ b2,
                             unsigned short* __restrict__ wout,
                             int IN_C, int OC, int OCP, int nelem) {
  int idx = blockIdx.x * 256 + threadIdx.x;
  if (idx >= nelem) return;
  int per_i = 3 * OCP * 40;
  int i = idx / per_i, r = idx - i * per_i;
  int c = r / (OCP * 40); r -= c * OCP * 40;
  int o = r / 40, kk = r - o * 40;
  float v = 0.f;
  if (kk < 32 && o < OC) {
    int hk = c * 32 + kk;
    if (hk < 90) v = w2[hk * (IN_C * OC) + i * OC + o];
    else if (hk == 90) v = b2[i * OC + o];
  }
  wout[idx] = rhu1(v);
}

// Fused message GEMM + scatter, i-outer decomposition:
//   tmp_i[e][o] = sum_hk he[e][hk] * W'[i][hk][o]   (3 chained MFMAs, he in regs)
//   acc[e][o]  += z[e][i] * tmp_i[e][o]             (f32 fmac on accumulator)
// A (he) loaded ONCE into 48 VGPRs; W' streamed per-i (reg prefetch -> ds_write);
// z gathered+transposed in LDS (bf16): one ds_read_b64 broadcast per (i,mt).
template <int ILIM, int OC, int OCP, int WNV, int WM>
__launch_bounds__(256, 2)
__global__ void msg_mfma(const unsigned short* __restrict__ he,
                         const float* __restrict__ nin,
                         const int* __restrict__ src, const int* __restrict__ dst,
                         const unsigned short* __restrict__ wp,
                         float* __restrict__ agg) {
  constexpr int WB = 3 * OCP * 40 * 2;      // bytes per i of W'
  constexpr int NW16 = WB / 16;             // 16B packets per i
  constexpr int NPT = (NW16 + 255) / 256;
  constexpr int ZST = 132;                  // z_sT row stride (shorts)
  __shared__ unsigned short z_sT[ILIM * ZST];   // [i][e] bf16
  __shared__ unsigned short w_s[3 * OCP * 40];
  __shared__ int dst_s[128];
  const int tid = threadIdx.x;
  const int e0 = blockIdx.x * 128;
  const int wid = tid >> 6, ln = tid & 15, q = (tid & 63) >> 4;
  const int wn = wid % WNV, wm = wid / WNV;
  const int eb = wm * (WM * 16);
  const int n0w = wn * 48;

  if (tid < 128) dst_s[tid] = dst[e0 + tid];

  // stage z transposed: z_sT[i][e] = bf16(nin[src[e]][i])
  {
    const int e = tid & 127, jj = tid >> 7;
    const int sn = src[e0 + e];
    const float* zr = nin + (size_t)sn * ILIM;
    for (int p = jj; p < ILIM / 2; p += 2) {
      const float2 v = *(const float2*)(zr + 2 * p);
      z_sT[(2 * p) * ZST + e]     = rhu1(v.x);
      z_sT[(2 * p + 1) * ZST + e] = rhu1(v.y);
    }
  }

  // A-fragments: raw bf16 he, register-resident for the whole kernel
  s16x8 af[WM][3];
#pragma unroll
  for (int mt = 0; mt < WM; mt++) {
    const unsigned short* hr = he + (size_t)(e0 + eb + mt * 16 + ln) * 96 + q * 8;
#pragma unroll
    for (int c = 0; c < 3; c++) af[mt][c] = *(const s16x8*)(hr + c * 32);
  }

  // W'(i=0): global -> regs -> LDS
  uint4 wreg[NPT];
#pragma unroll
  for (int p = 0; p < NPT; p++) {
    int t = tid + p * 256;
    if (t < NW16) wreg[p] = *(const uint4*)(wp + t * 8);
  }
#pragma unroll
  for (int p = 0; p < NPT; p++) {
    int t = tid + p * 256;
    if (t < NW16) *(uint4*)((char*)w_s + t * 16) = wreg[p];
  }
  __syncthreads();

  f32x4 acc[WM][3];
#pragma unroll
  for (int mt = 0; mt < WM; mt++)
#pragma unroll
    for (int nt = 0; nt < 3; nt++) acc[mt][nt] = (f32x4)0.f;
  const f32x4 fz = (f32x4)0.f;

  for (int i = 0; i < ILIM; i++) {
    // prefetch W'(i+1) into registers (in flight across the MFMA block)
    if (i + 1 < ILIM) {
      const unsigned short* wg = wp + (size_t)(i + 1) * (3 * OCP * 40);
#pragma unroll
      for (int p = 0; p < NPT; p++) {
        int t = tid + p * 256;
        if (t < NW16) wreg[p] = *(const uint4*)(wg + t * 8);
      }
    }
    // z for this i: one b64 broadcast per mt -> 4 f32 rows
    f32x4 zv[WM];
#pragma unroll
    for (int mt = 0; mt < WM; mt++) {
      const uint2 u = *(const uint2*)&z_sT[i * ZST + eb + mt * 16 + q * 4];
      zv[mt][0] = bflo(u.x); zv[mt][1] = bfhi(u.x);
      zv[mt][2] = bflo(u.y); zv[mt][3] = bfhi(u.y);
    }
#pragma unroll
    for (int nt = 0; nt < 3; nt++) {
      const int ob = (n0w + nt * 16 + ln) * 40 + q * 8;
      const s16x8 b0 = *(const s16x8*)&w_s[ob];
      const s16x8 b1 = *(const s16x8*)&w_s[OCP * 40 + ob];
      const s16x8 b2v = *(const s16x8*)&w_s[2 * OCP * 40 + ob];
#pragma unroll
      for (int mt = 0; mt < WM; mt++) {
        f32x4 t = __builtin_amdgcn_mfma_f32_16x16x32_bf16(af[mt][0], b0, fz, 0, 0, 0);
        t = __builtin_amdgcn_mfma_f32_16x16x32_bf16(af[mt][1], b1, t, 0, 0, 0);
        t = __builtin_amdgcn_mfma_f32_16x16x32_bf16(af[mt][2], b2v, t, 0, 0, 0);
        acc[mt][nt] += zv[mt] * t;
      }
    }
    if (i + 1 < ILIM) {
      __syncthreads();   // all reads of w_s done
#pragma unroll
      for (int p = 0; p < NPT; p++) {
        int t = tid + p * 256;
        if (t < NW16) *(uint4*)((char*)w_s + t * 16) = wreg[p];
      }
      __syncthreads();   // w_s(i+1) visible
    }
  }

  // epilogue: D[row=q*4+r][col=ln] -> atomicAdd agg[dst]
#pragma unroll
  for (int mt = 0; mt < WM; mt++) {
#pragma unroll
    for (int nt = 0; nt < 3; nt++) {
      int o = n0w + nt * 16 + ln;
      if (o < OC) {
#pragma unroll
        for (int r = 0; r < 4; r++) {
          int el = eb + mt * 16 + q * 4 + r;
          atomicAdd(agg + (size_t)dst_s[el] * OC + o, acc[mt][nt][r]);
        }
      }
    }
  }
}

// out[n][o] = relu(agg[n][o] + sum_i nin[n][i]*root[i][o] + bias[o])   (fp32 exact)
template <int IN_C, int OC>
__global__ void node_kernel(const float* __restrict__ agg, const float* __restrict__ nin,
                            const float* __restrict__ root, const float* __restrict__ bias,
                            float* __restrict__ out) {
  int idx = blockIdx.x * 256 + threadIdx.x;
  if (idx >= NN * OC) return;
  int n = idx / OC, o = idx - n * OC;
  float acc = agg[idx] + bias[o];
  const float* inp = nin + (size_t)n * IN_C;
#pragma unroll 6
  for (int i = 0; i < IN_C; i++) acc = fmaf(inp[i], root[i * OC + o], acc);
  out[idx] = fmaxf(acc, 0.f);
}

// per-graph: pool (batch sorted -> binary search) + fc1 + out
__global__ void pool_mlp_kernel(const float* __restrict__ h3, const int* __restrict__ batch,
                                const float* __restrict__ fc1_w, const float* __restrict__ fc1_b,
                                const float* __restrict__ out_w, const float* __restrict__ out_b,
                                float* __restrict__ out) {
  const int b = blockIdx.x;
  const int tid = threadIdx.x;
  __shared__ float g[45];
  __shared__ float go[90];
  __shared__ int rng[2];
  if (tid < 2) {
    int target = b + tid;
    int lo = 0, hi = NN;
    while (lo < hi) { int mid = (lo + hi) >> 1; if (batch[mid] < target) lo = mid + 1; else hi = mid; }
    rng[tid] = lo;
  }
  __syncthreads();
  const int s = rng[0], e = rng[1];
  if (tid < 45) {
    float acc = 0.f;
    for (int n = s; n < e; n++) acc += h3[n * 45 + tid];
    g[tid] = acc;
  }
  __syncthreads();
  if (tid < 90) {
    float acc = fc1_b[tid];
#pragma unroll 5
    for (int i = 0; i < 45; i++) acc = fmaf(g[i], fc1_w[i * 90 + tid], acc);
    go[tid] = fmaxf(acc, 0.f) * out_w[tid];
  }
  __syncthreads();
  if (tid == 0) {
    float acc = out_b[0];
    for (int i = 0; i < 90; i++) acc += go[i];
    out[b] = acc;
  }
}

extern "C" void kernel_launch(void* const* d_in, const int* in_sizes, int n_in,
                              void* d_out, int out_size, void* d_ws, size_t ws_size,
                              hipStream_t stream) {
  const float* x       = (const float*)d_in[0];
  const float* pos     = (const float*)d_in[1];
  const float* ea      = (const float*)d_in[2];
  const int*   eidx    = (const int*)d_in[3];
  const int*   batch   = (const int*)d_in[4];
  const float* c1_w1   = (const float*)d_in[5];
  const float* c1_b1   = (const float*)d_in[6];
  const float* c1_w2   = (const float*)d_in[7];
  const float* c1_b2   = (const float*)d_in[8];
  const float* c1_root = (const float*)d_in[9];
  const float* c1_bias = (const float*)d_in[10];
  const float* c2_w1   = (const float*)d_in[11];
  const float* c2_b1   = (const float*)d_in[12];
  const float* c2_w2   = (const float*)d_in[13];
  const float* c2_b2   = (const float*)d_in[14];
  const float* c2_root = (const float*)d_in[15];
  const float* c2_bias = (const float*)d_in[16];
  const float* c3_w1   = (const float*)d_in[17];
  const float* c3_b1   = (const float*)d_in[18];
  const float* c3_w2   = (const float*)d_in[19];
  const float* c3_b2   = (const float*)d_in[20];
  const float* c3_root = (const float*)d_in[21];
  const float* c3_bias = (const float*)d_in[22];
  const float* fc1_w   = (const float*)d_in[23];
  const float* fc1_b   = (const float*)d_in[24];
  const float* out_w   = (const float*)d_in[25];
  const float* out_b   = (const float*)d_in[26];
  const int* src = eidx;
  const int* dst = eidx + NE;

  // workspace carve
  float* ws  = (float*)d_ws;
  float* h0  = ws;                       // NN*16
  float* h1  = h0 + NN * 16;             // NN*90
  float* h2  = h1 + NN * 90;             // NN*90
  float* h3  = h2 + NN * 90;             // NN*45
  float* agg = h3 + NN * 45;             // NN*90
  unsigned short* he_bf = (unsigned short*)(agg + NN * 90);   // NE*96
  unsigned short* wp1 = he_bf + (size_t)NE * 96;              // 16*3*96*40
  unsigned short* wp2 = wp1 + 16 * 3 * 96 * 40;               // 90*3*96*40
  unsigned short* wp3 = wp2 + 90 * 3 * 96 * 40;               // 90*3*48*40

  concat_kernel<<<(NN * 16) / 256, 256, 0, stream>>>(x, pos, h0);

  wprep_kernel<<<(16 * 3 * 96 * 40) / 256, 256, 0, stream>>>(c1_w2, c1_b2, wp1, 16, 90, 96, 16 * 3 * 96 * 40);
  wprep_kernel<<<(90 * 3 * 96 * 40) / 256, 256, 0, stream>>>(c2_w2, c2_b2, wp2, 90, 90, 96, 90 * 3 * 96 * 40);
  wprep_kernel<<<(90 * 3 * 48 * 40) / 256, 256, 0, stream>>>(c3_w2, c3_b2, wp3, 90, 45, 48, 90 * 3 * 48 * 40);

  // conv1: 16 -> 90
  hipMemsetAsync(agg, 0, (size_t)NN * 90 * sizeof(float), stream);
  edge_mlp_bf<<<(NE * 96) / 256, 256, 0, stream>>>(ea, c1_w1, c1_b1, he_bf);
  msg_mfma<16, 90, 96, 2, 4><<<NE / 128, 256, 0, stream>>>(he_bf, h0, src, dst, wp1, agg);
  node_kernel<16, 90><<<(NN * 90) / 256, 256, 0, stream>>>(agg, h0, c1_root, c1_bias, h1);

  // conv2: 90 -> 90
  hipMemsetAsync(agg, 0, (size_t)NN * 90 * sizeof(float), stream);
  edge_mlp_bf<<<(NE * 96) / 256, 256, 0, stream>>>(ea, c2_w1, c2_b1, he_bf);
  msg_mfma<90, 90, 96, 2, 4><<<NE / 128, 256, 0, stream>>>(he_bf, h1, src, dst, wp2, agg);
  node_kernel<90, 90><<<(NN * 90) / 256, 256, 0, stream>>>(agg, h1, c2_root, c2_bias, h2);

  // conv3: 90 -> 45  (WNV=1, WM=2: 4 waves all span o, 128 edges)
  hipMemsetAsync(agg, 0, (size_t)NN * 45 * sizeof(float), stream);
  edge_mlp_bf<<<(NE * 96) / 256, 256, 0, stream>>>(ea, c3_w1, c3_b1, he_bf);
  msg_mfma<90, 45, 48, 1, 2><<<NE / 128, 256, 0, stream>>>(he_bf, h2, src, dst, wp3, agg);
  node_kernel<90, 45><<<(NN * 45 + 255) / 256, 256, 0, stream>>>(agg, h2, c3_root, c3_bias, h3);

  pool_mlp_kernel<<<NG, 128, 0, stream>>>(h3, batch, fc1_w, fc1_b, out_w, out_b, (float*)d_out);
}

// Round 5
// 840.620 us; speedup vs baseline: 1.0442x; 1.0442x over previous
//
#include <hip/hip_runtime.h>

#define NN 16000   // nodes
#define NE 64000   // edges
#define HD 90      // hidden
#define NG 512     // graphs

typedef float f32x4 __attribute__((ext_vector_type(4)));
typedef short s16x8 __attribute__((ext_vector_type(8)));

// round-half-up f32 -> bf16
__device__ __forceinline__ unsigned short rhu1(float f) {
  return (unsigned short)((__builtin_bit_cast(unsigned int, f) + 0x8000u) >> 16);
}
// pack two f32 -> bf16x2 (lo in low half), RHU rounding
__device__ __forceinline__ unsigned int rhu_pack(float lo, float hi) {
  unsigned int ul = __builtin_bit_cast(unsigned int, lo) + 0x8000u;
  unsigned int uh = __builtin_bit_cast(unsigned int, hi) + 0x8000u;
  return __builtin_amdgcn_perm(uh, ul, 0x07060302u);
}

// h0 = concat(x, pos) : [NN, 16]
__global__ void concat_kernel(const float* __restrict__ x, const float* __restrict__ pos,
                              float* __restrict__ h0) {
  int idx = blockIdx.x * 256 + threadIdx.x;
  if (idx >= NN * 16) return;
  int n = idx >> 4, c = idx & 15;
  h0[idx] = (c < 13) ? x[n * 13 + c] : pos[n * 3 + (c - 13)];
}

// he_bf[e][k] : [NE, 96] bf16. k<90: relu(edge MLP); k==90: 1.0 (bias row); k>90: 0
__global__ void edge_mlp_bf(const float* __restrict__ ea, const float* __restrict__ w1,
                            const float* __restrict__ b1, unsigned short* __restrict__ he) {
  int idx = blockIdx.x * 256 + threadIdx.x;
  if (idx >= NE * 96) return;
  int e = idx / 96, k = idx - e * 96;
  unsigned short v;
  if (k < 90) {
    const float* a = ea + e * 8;
    float acc = b1[k];
#pragma unroll
    for (int j = 0; j < 8; j++) acc = fmaf(a[j], w1[j * HD + k], acc);
    v = rhu1(fmaxf(acc, 0.f));
  } else {
    v = (k == 90) ? (unsigned short)0x3F80 : (unsigned short)0;  // bf16(1.0) / 0
  }
  he[idx] = v;
}

// W' prep in MFMA-B-fragment order: shorts laid out as
//   [i][tile t(NTT)][chunk c(3)][lane(64)][j(8)]
// value(i,t,c,lane,j): hk=c*32+(lane>>4)*8+j, o=t*16+(lane&15);
//   hk<90 -> w2[hk][i*OC+o]; hk==90 -> b2[i*OC+o]; else 0.   One block per (i,c).
template <int OC, int NTT>
__global__ void wprep_frag(const float* __restrict__ w2, const float* __restrict__ b2,
                           unsigned short* __restrict__ wout, int inc_oc) {
  const int i = blockIdx.x / 3, c = blockIdx.x - 3 * (blockIdx.x / 3);
  __shared__ float t_s[32 * 100];
  const int tid = threadIdx.x;
  for (int idx = tid; idx < 32 * 96; idx += 256) {
    int kk = idx / 96, o = idx - kk * 96;
    int hk = c * 32 + kk;
    float v = 0.f;
    if (o < OC) {
      if (hk < 90) v = w2[hk * inc_oc + i * OC + o];        // coalesced along o
      else if (hk == 90) v = b2[i * OC + o];
    }
    t_s[kk * 100 + o] = v;
  }
  __syncthreads();
  unsigned int* wo = (unsigned int*)(wout + (size_t)i * NTT * 3 * 512) + c * 256;
  for (int idx = tid; idx < NTT * 256; idx += 256) {
    int t = idx >> 8, r = idx & 255;
    int lane = r >> 2, u = r & 3;
    int kk = (lane >> 4) * 8 + 2 * u;
    int o = t * 16 + (lane & 15);
    wo[(size_t)t * 3 * 256 + lane * 4 + u] = rhu_pack(t_s[kk * 100 + o], t_s[(kk + 1) * 100 + o]);
  }
}

// Fused message GEMM + scatter, i-outer, barrier-free K-loop:
//   tmp_i[e][o] = sum_hk he[e][hk] * W'[i][hk][o]   (3 chained MFMAs; he in 48 regs)
//   acc[e][o]  += z[e][i] * tmp_i[e][o]             (f32 fma; z f32 from LDS)
// W' B-fragments loaded straight global(L2)->VGPR, register double-buffered.
template <int ILIM, int OC, int NTT, int BLK, int WNV, int WM>
__global__ __launch_bounds__(BLK) __attribute__((amdgpu_waves_per_eu(2, 2)))
void msg_mfma(const unsigned short* __restrict__ he,
              const float* __restrict__ nin,
              const int* __restrict__ src, const int* __restrict__ dst,
              const unsigned short* __restrict__ wp,
              float* __restrict__ agg) {
  constexpr int ZST = 132;                 // z_sT row stride (floats)
  constexpr int IST = NTT * 3 * 512;       // W' shorts per i
  __shared__ float z_sT[ILIM * ZST];       // [i][e] f32
  __shared__ int dst_s[128];
  const int tid = threadIdx.x;
  const int e0 = blockIdx.x * 128;
  const int wid = tid >> 6, l = tid & 63, ln = tid & 15, q = (tid & 63) >> 4;
  const int wn = wid % WNV, wm = wid / WNV;
  const int eb = wm * (WM * 16);

  if (tid < 128) dst_s[tid] = dst[e0 + tid];

  // stage z transposed (f32): z_sT[i][e] = nin[src[e]][i]
  {
    constexpr int TPE = BLK / 128;
    const int e = tid % 128, jj = tid / 128;
    const float* zr = nin + (size_t)src[e0 + e] * ILIM;
    for (int p = jj; p < ILIM / 2; p += TPE) {
      const float2 v = *(const float2*)(zr + 2 * p);
      z_sT[(2 * p) * ZST + e] = v.x;
      z_sT[(2 * p + 1) * ZST + e] = v.y;
    }
  }

  // A-fragments: raw bf16 he, register-resident for the whole kernel
  s16x8 af[WM][3];
#pragma unroll
  for (int mt = 0; mt < WM; mt++) {
    const unsigned short* hr = he + (size_t)(e0 + eb + mt * 16 + ln) * 96 + q * 8;
#pragma unroll
    for (int c = 0; c < 3; c++) af[mt][c] = *(const s16x8*)(hr + c * 32);
  }

  // wave's 9 B-fragment pointers: base + t*512 shorts (t = ntl*3+c), + i*IST
  const unsigned short* wbase = wp + (size_t)(wn * 3) * 3 * 512 + l * 8;
  uint4 ba[9], bb[9];
#pragma unroll
  for (int t = 0; t < 9; t++) ba[t] = *(const uint4*)(wbase + t * 512);

  __syncthreads();   // z_sT/dst_s ready; no barriers after this

  f32x4 acc[WM][3];
#pragma unroll
  for (int mt = 0; mt < WM; mt++)
#pragma unroll
    for (int nt = 0; nt < 3; nt++) acc[mt][nt] = (f32x4)0.f;

  auto body = [&](int i, uint4 (&buf)[9]) {
    f32x4 zv[WM];
#pragma unroll
    for (int mt = 0; mt < WM; mt++)
      zv[mt] = *(const f32x4*)&z_sT[i * ZST + eb + mt * 16 + q * 4];
#pragma unroll
    for (int ntl = 0; ntl < 3; ntl++) {
      const s16x8 b0 = __builtin_bit_cast(s16x8, buf[ntl * 3 + 0]);
      const s16x8 b1 = __builtin_bit_cast(s16x8, buf[ntl * 3 + 1]);
      const s16x8 b2v = __builtin_bit_cast(s16x8, buf[ntl * 3 + 2]);
#pragma unroll
      for (int mt = 0; mt < WM; mt++) {
        f32x4 t = __builtin_amdgcn_mfma_f32_16x16x32_bf16(af[mt][0], b0, (f32x4)0.f, 0, 0, 0);
        t = __builtin_amdgcn_mfma_f32_16x16x32_bf16(af[mt][1], b1, t, 0, 0, 0);
        t = __builtin_amdgcn_mfma_f32_16x16x32_bf16(af[mt][2], b2v, t, 0, 0, 0);
        acc[mt][ntl] += zv[mt] * t;
      }
    }
  };

  for (int i = 0; i < ILIM; i += 2) {
    if (i + 1 < ILIM) {
      const unsigned short* wg = wbase + (size_t)(i + 1) * IST;
#pragma unroll
      for (int t = 0; t < 9; t++) bb[t] = *(const uint4*)(wg + t * 512);
    }
    body(i, ba);
    if (i + 1 < ILIM) {
      if (i + 2 < ILIM) {
        const unsigned short* wg = wbase + (size_t)(i + 2) * IST;
#pragma unroll
        for (int t = 0; t < 9; t++) ba[t] = *(const uint4*)(wg + t * 512);
      }
      body(i + 1, bb);
    }
  }

  // epilogue: D[row=q*4+r][col=ln] -> atomicAdd agg[dst]
#pragma unroll
  for (int mt = 0; mt < WM; mt++) {
#pragma unroll
    for (int ntl = 0; ntl < 3; ntl++) {
      int o = wn * 48 + ntl * 16 + ln;
      if (o < OC) {
#pragma unroll
        for (int r = 0; r < 4; r++) {
          int el = eb + mt * 16 + q * 4 + r;
          atomicAdd(agg + (size_t)dst_s[el] * OC + o, acc[mt][ntl][r]);
        }
      }
    }
  }
}

// out[n][o] = relu(agg[n][o] + sum_i nin[n][i]*root[i][o] + bias[o])   (fp32 exact)
template <int IN_C, int OC>
__global__ void node_kernel(const float* __restrict__ agg, const float* __restrict__ nin,
                            const float* __restrict__ root, const float* __restrict__ bias,
                            float* __restrict__ out) {
  int idx = blockIdx.x * 256 + threadIdx.x;
  if (idx >= NN * OC) return;
  int n = idx / OC, o = idx - n * OC;
  float acc = agg[idx] + bias[o];
  const float* inp = nin + (size_t)n * IN_C;
#pragma unroll 6
  for (int i = 0; i < IN_C; i++) acc = fmaf(inp[i], root[i * OC + o], acc);
  out[idx] = fmaxf(acc, 0.f);
}

// per-graph: pool (batch sorted -> binary search) + fc1 + out
__global__ void pool_mlp_kernel(const float* __restrict__ h3, const int* __restrict__ batch,
                                const float* __restrict__ fc1_w, const float* __restrict__ fc1_b,
                                const float* __restrict__ out_w, const float* __restrict__ out_b,
                                float* __restrict__ out) {
  const int b = blockIdx.x;
  const int tid = threadIdx.x;
  __shared__ float g[45];
  __shared__ float go[90];
  __shared__ int rng[2];
  if (tid < 2) {
    int target = b + tid;
    int lo = 0, hi = NN;
    while (lo < hi) { int mid = (lo + hi) >> 1; if (batch[mid] < target) lo = mid + 1; else hi = mid; }
    rng[tid] = lo;
  }
  __syncthreads();
  const int s = rng[0], e = rng[1];
  if (tid < 45) {
    float acc = 0.f;
    for (int n = s; n < e; n++) acc += h3[n * 45 + tid];
    g[tid] = acc;
  }
  __syncthreads();
  if (tid < 90) {
    float acc = fc1_b[tid];
#pragma unroll 5
    for (int i = 0; i < 45; i++) acc = fmaf(g[i], fc1_w[i * 90 + tid], acc);
    go[tid] = fmaxf(acc, 0.f) * out_w[tid];
  }
  __syncthreads();
  if (tid == 0) {
    float acc = out_b[0];
    for (int i = 0; i < 90; i++) acc += go[i];
    out[b] = acc;
  }
}

extern "C" void kernel_launch(void* const* d_in, const int* in_sizes, int n_in,
                              void* d_out, int out_size, void* d_ws, size_t ws_size,
                              hipStream_t stream) {
  const float* x       = (const float*)d_in[0];
  const float* pos     = (const float*)d_in[1];
  const float* ea      = (const float*)d_in[2];
  const int*   eidx    = (const int*)d_in[3];
  const int*   batch   = (const int*)d_in[4];
  const float* c1_w1   = (const float*)d_in[5];
  const float* c1_b1   = (const float*)d_in[6];
  const float* c1_w2   = (const float*)d_in[7];
  const float* c1_b2   = (const float*)d_in[8];
  const float* c1_root = (const float*)d_in[9];
  const float* c1_bias = (const float*)d_in[10];
  const float* c2_w1   = (const float*)d_in[11];
  const float* c2_b1   = (const float*)d_in[12];
  const float* c2_w2   = (const float*)d_in[13];
  const float* c2_b2   = (const float*)d_in[14];
  const float* c2_root = (const float*)d_in[15];
  const float* c2_bias = (const float*)d_in[16];
  const float* c3_w1   = (const float*)d_in[17];
  const float* c3_b1   = (const float*)d_in[18];
  const float* c3_w2   = (const float*)d_in[19];
  const float* c3_b2   = (const float*)d_in[20];
  const float* c3_root = (const float*)d_in[21];
  const float* c3_bias = (const float*)d_in[22];
  const float* fc1_w   = (const float*)d_in[23];
  const float* fc1_b   = (const float*)d_in[24];
  const float* out_w   = (const float*)d_in[25];
  const float* out_b   = (const float*)d_in[26];
  const int* src = eidx;
  const int* dst = eidx + NE;

  // workspace carve
  float* ws  = (float*)d_ws;
  float* h0  = ws;                       // NN*16
  float* h1  = h0 + NN * 16;             // NN*90
  float* h2  = h1 + NN * 90;             // NN*90
  float* h3  = h2 + NN * 90;             // NN*45
  float* agg = h3 + NN * 45;             // NN*90
  unsigned short* he_bf = (unsigned short*)(agg + NN * 90);   // NE*96
  unsigned short* wp1 = he_bf + (size_t)NE * 96;              // 16*6*3*512
  unsigned short* wp2 = wp1 + (size_t)16 * 6 * 3 * 512;       // 90*6*3*512
  unsigned short* wp3 = wp2 + (size_t)90 * 6 * 3 * 512;       // 90*3*3*512

  concat_kernel<<<(NN * 16) / 256, 256, 0, stream>>>(x, pos, h0);

  wprep_frag<90, 6><<<16 * 3, 256, 0, stream>>>(c1_w2, c1_b2, wp1, 16 * 90);
  wprep_frag<90, 6><<<90 * 3, 256, 0, stream>>>(c2_w2, c2_b2, wp2, 90 * 90);
  wprep_frag<45, 3><<<90 * 3, 256, 0, stream>>>(c3_w2, c3_b2, wp3, 90 * 45);

  // conv1: 16 -> 90
  hipMemsetAsync(agg, 0, (size_t)NN * 90 * sizeof(float), stream);
  edge_mlp_bf<<<(NE * 96) / 256, 256, 0, stream>>>(ea, c1_w1, c1_b1, he_bf);
  msg_mfma<16, 90, 6, 256, 2, 4><<<NE / 128, 256, 0, stream>>>(he_bf, h0, src, dst, wp1, agg);
  node_kernel<16, 90><<<(NN * 90) / 256, 256, 0, stream>>>(agg, h0, c1_root, c1_bias, h1);

  // conv2: 90 -> 90
  hipMemsetAsync(agg, 0, (size_t)NN * 90 * sizeof(float), stream);
  edge_mlp_bf<<<(NE * 96) / 256, 256, 0, stream>>>(ea, c2_w1, c2_b1, he_bf);
  msg_mfma<90, 90, 6, 256, 2, 4><<<NE / 128, 256, 0, stream>>>(he_bf, h1, src, dst, wp2, agg);
  node_kernel<90, 90><<<(NN * 90) / 256, 256, 0, stream>>>(agg, h1, c2_root, c2_bias, h2);

  // conv3: 90 -> 45  (2-wave blocks, both waves span all 3 o-tiles, 128 edges)
  hipMemsetAsync(agg, 0, (size_t)NN * 45 * sizeof(float), stream);
  edge_mlp_bf<<<(NE * 96) / 256, 256, 0, stream>>>(ea, c3_w1, c3_b1, he_bf);
  msg_mfma<90, 45, 3, 128, 1, 4><<<NE / 128, 128, 0, stream>>>(he_bf, h2, src, dst, wp3, agg);
  node_kernel<90, 45><<<(NN * 45 + 255) / 256, 256, 0, stream>>>(agg, h2, c3_root, c3_bias, h3);

  pool_mlp_kernel<<<NG, 128, 0, stream>>>(h3, batch, fc1_w, fc1_b, out_w, out_b, (float*)d_out);
}

// Round 6
// 826.074 us; speedup vs baseline: 1.0626x; 1.0176x over previous
//
#include <hip/hip_runtime.h>

#define NN 16000   // nodes
#define NE 64000   // edges
#define HD 90      // hidden
#define NG 512     // graphs

typedef float f32x4 __attribute__((ext_vector_type(4)));
typedef short s16x8 __attribute__((ext_vector_type(8)));

// round-half-up f32 -> bf16
__device__ __forceinline__ unsigned short rhu1(float f) {
  return (unsigned short)((__builtin_bit_cast(unsigned int, f) + 0x8000u) >> 16);
}
// pack two f32 -> bf16x2 (lo in low half), RHU rounding
__device__ __forceinline__ unsigned int rhu_pack(float lo, float hi) {
  unsigned int ul = __builtin_bit_cast(unsigned int, lo) + 0x8000u;
  unsigned int uh = __builtin_bit_cast(unsigned int, hi) + 0x8000u;
  return __builtin_amdgcn_perm(uh, ul, 0x07060302u);
}

// h0 = concat(x, pos) : [NN, 16]
__global__ void concat_kernel(const float* __restrict__ x, const float* __restrict__ pos,
                              float* __restrict__ h0) {
  int idx = blockIdx.x * 256 + threadIdx.x;
  if (idx >= NN * 16) return;
  int n = idx >> 4, c = idx & 15;
  h0[idx] = (c < 13) ? x[n * 13 + c] : pos[n * 3 + (c - 13)];
}

// he_bf[e][k] : [NE, 96] bf16. k<90: relu(edge MLP); k==90: 1.0 (bias row); k>90: 0
__global__ void edge_mlp_bf(const float* __restrict__ ea, const float* __restrict__ w1,
                            const float* __restrict__ b1, unsigned short* __restrict__ he) {
  int idx = blockIdx.x * 256 + threadIdx.x;
  if (idx >= NE * 96) return;
  int e = idx / 96, k = idx - e * 96;
  unsigned short v;
  if (k < 90) {
    const float* a = ea + e * 8;
    float acc = b1[k];
#pragma unroll
    for (int j = 0; j < 8; j++) acc = fmaf(a[j], w1[j * HD + k], acc);
    v = rhu1(fmaxf(acc, 0.f));
  } else {
    v = (k == 90) ? (unsigned short)0x3F80 : (unsigned short)0;  // bf16(1.0) / 0
  }
  he[idx] = v;
}

// W' prep in MFMA-B-fragment order: shorts laid out as
//   [i][tile t(NTT)][chunk c(3)][lane(64)][j(8)]
// value(i,t,c,lane,j): hk=c*32+(lane>>4)*8+j, o=t*16+(lane&15);
//   hk<90 -> w2[hk][i*OC+o]; hk==90 -> b2[i*OC+o]; else 0.   One block per (i,c).
template <int OC, int NTT>
__global__ void wprep_frag(const float* __restrict__ w2, const float* __restrict__ b2,
                           unsigned short* __restrict__ wout, int inc_oc) {
  const int i = blockIdx.x / 3, c = blockIdx.x - 3 * (blockIdx.x / 3);
  __shared__ float t_s[32 * 100];
  const int tid = threadIdx.x;
  for (int idx = tid; idx < 32 * 96; idx += 256) {
    int kk = idx / 96, o = idx - kk * 96;
    int hk = c * 32 + kk;
    float v = 0.f;
    if (o < OC) {
      if (hk < 90) v = w2[hk * inc_oc + i * OC + o];        // coalesced along o
      else if (hk == 90) v = b2[i * OC + o];
    }
    t_s[kk * 100 + o] = v;
  }
  __syncthreads();
  unsigned int* wo = (unsigned int*)(wout + (size_t)i * NTT * 3 * 512) + c * 256;
  for (int idx = tid; idx < NTT * 256; idx += 256) {
    int t = idx >> 8, r = idx & 255;
    int lane = r >> 2, u = r & 3;
    int kk = (lane >> 4) * 8 + 2 * u;
    int o = t * 16 + (lane & 15);
    wo[(size_t)t * 3 * 256 + lane * 4 + u] = rhu_pack(t_s[kk * 100 + o], t_s[(kk + 1) * 100 + o]);
  }
}

// pipeline-stage macros (textual: plain arrays, constant indices after unroll —
// NO lambdas / array references, which caused round-5's alloca->scratch spill)
#define MSG_PREFETCH(II, BUF)                                                  \
  do {                                                                         \
    const unsigned short* wg_ = wbase + (size_t)(II) * IST;                    \
    _Pragma("unroll")                                                          \
    for (int t_ = 0; t_ < 9; t_++) BUF[t_] = *(const uint4*)(wg_ + t_ * 512);  \
  } while (0)

#define MSG_BODY(II, BUF)                                                      \
  do {                                                                         \
    f32x4 zv[WM];                                                              \
    _Pragma("unroll")                                                          \
    for (int mt = 0; mt < WM; mt++)                                            \
      zv[mt] = *(const f32x4*)&z_sT[(II) * ZST + eb + mt * 16 + q * 4];        \
    _Pragma("unroll")                                                          \
    for (int ntl = 0; ntl < 3; ntl++) {                                        \
      const s16x8 wb0 = __builtin_bit_cast(s16x8, BUF[ntl * 3 + 0]);           \
      const s16x8 wb1 = __builtin_bit_cast(s16x8, BUF[ntl * 3 + 1]);           \
      const s16x8 wb2 = __builtin_bit_cast(s16x8, BUF[ntl * 3 + 2]);           \
      _Pragma("unroll")                                                        \
      for (int mt = 0; mt < WM; mt++) {                                        \
        f32x4 t_ = __builtin_amdgcn_mfma_f32_16x16x32_bf16(af[mt][0], wb0,     \
                                                           (f32x4)0.f, 0, 0, 0); \
        t_ = __builtin_amdgcn_mfma_f32_16x16x32_bf16(af[mt][1], wb1, t_, 0, 0, 0); \
        t_ = __builtin_amdgcn_mfma_f32_16x16x32_bf16(af[mt][2], wb2, t_, 0, 0, 0); \
        acc[mt][ntl] += zv[mt] * t_;                                           \
      }                                                                        \
    }                                                                          \
  } while (0)

// Fused message GEMM + scatter, i-outer, barrier-free K-loop:
//   tmp_i[e][o] = sum_hk he[e][hk] * W'[i][hk][o]   (3 chained MFMAs; he in regs)
//   acc[e][o]  += z[e][i] * tmp_i[e][o]             (f32 fma; z f32 from LDS)
// W' B-fragments loaded straight global(L2)->VGPR, register double-buffered over i.
// Block: 128 edges, 4 waves; wave = WM m-tiles x 3 n-tiles (wn selects n-half).
template <int ILIM, int OC, int NTT, int WNV, int WM>
__global__ __launch_bounds__(256, 2)
void msg_mfma(const unsigned short* __restrict__ he,
              const float* __restrict__ nin,
              const int* __restrict__ src, const int* __restrict__ dst,
              const unsigned short* __restrict__ wp,
              float* __restrict__ agg) {
  constexpr int ZST = 132;                 // z_sT row stride (floats)
  constexpr int IST = NTT * 3 * 512;       // W' shorts per i
  __shared__ float z_sT[ILIM * ZST];       // [i][e] f32
  __shared__ int dst_s[128];
  const int tid = threadIdx.x;
  const int e0 = blockIdx.x * 128;
  const int wid = tid >> 6, l = tid & 63, ln = tid & 15, q = (tid & 63) >> 4;
  const int wn = wid % WNV, wm = wid / WNV;
  const int eb = wm * (WM * 16);

  if (tid < 128) dst_s[tid] = dst[e0 + tid];

  // stage z transposed (f32): z_sT[i][e] = nin[src[e]][i]
  {
    const int e = tid & 127, jj = tid >> 7;
    const float* zr = nin + (size_t)src[e0 + e] * ILIM;
    for (int p = jj; p < ILIM / 2; p += 2) {
      const float2 v = *(const float2*)(zr + 2 * p);
      z_sT[(2 * p) * ZST + e] = v.x;
      z_sT[(2 * p + 1) * ZST + e] = v.y;
    }
  }

  // A-fragments: raw bf16 he, register-resident for the whole kernel
  s16x8 af[WM][3];
#pragma unroll
  for (int mt = 0; mt < WM; mt++) {
    const unsigned short* hr = he + (size_t)(e0 + eb + mt * 16 + ln) * 96 + q * 8;
#pragma unroll
    for (int c = 0; c < 3; c++) af[mt][c] = *(const s16x8*)(hr + c * 32);
  }

  // wave's 9 B-fragment base: tile T = wn*3 + ntl, chunk c -> offset (T*3+c)*512
  const unsigned short* wbase = wp + (size_t)(wn * 3) * 3 * 512 + l * 8;
  uint4 ba[9], bb[9];
  MSG_PREFETCH(0, ba);

  __syncthreads();   // z_sT/dst_s ready; no barriers after this

  f32x4 acc[WM][3];
#pragma unroll
  for (int mt = 0; mt < WM; mt++)
#pragma unroll
    for (int nt = 0; nt < 3; nt++) acc[mt][nt] = (f32x4)0.f;

  for (int i = 0; i < ILIM; i += 2) {
    if (i + 1 < ILIM) MSG_PREFETCH(i + 1, bb);
    MSG_BODY(i, ba);
    if (i + 1 < ILIM) {
      if (i + 2 < ILIM) MSG_PREFETCH(i + 2, ba);
      MSG_BODY(i + 1, bb);
    }
  }

  // epilogue: D[row=q*4+r][col=ln] -> atomicAdd agg[dst]
#pragma unroll
  for (int mt = 0; mt < WM; mt++) {
#pragma unroll
    for (int ntl = 0; ntl < 3; ntl++) {
      int o = wn * 48 + ntl * 16 + ln;
      if (o < OC) {
#pragma unroll
        for (int r = 0; r < 4; r++) {
          int el = eb + mt * 16 + q * 4 + r;
          atomicAdd(agg + (size_t)dst_s[el] * OC + o, acc[mt][ntl][r]);
        }
      }
    }
  }
}

// out[n][o] = relu(agg[n][o] + sum_i nin[n][i]*root[i][o] + bias[o])   (fp32 exact)
template <int IN_C, int OC>
__global__ void node_kernel(const float* __restrict__ agg, const float* __restrict__ nin,
                            const float* __restrict__ root, const float* __restrict__ bias,
                            float* __restrict__ out) {
  int idx = blockIdx.x * 256 + threadIdx.x;
  if (idx >= NN * OC) return;
  int n = idx / OC, o = idx - n * OC;
  float acc = agg[idx] + bias[o];
  const float* inp = nin + (size_t)n * IN_C;
#pragma unroll 6
  for (int i = 0; i < IN_C; i++) acc = fmaf(inp[i], root[i * OC + o], acc);
  out[idx] = fmaxf(acc, 0.f);
}

// per-graph: pool (batch sorted -> binary search) + fc1 + out
__global__ void pool_mlp_kernel(const float* __restrict__ h3, const int* __restrict__ batch,
                                const float* __restrict__ fc1_w, const float* __restrict__ fc1_b,
                                const float* __restrict__ out_w, const float* __restrict__ out_b,
                                float* __restrict__ out) {
  const int b = blockIdx.x;
  const int tid = threadIdx.x;
  __shared__ float g[45];
  __shared__ float go[90];
  __shared__ int rng[2];
  if (tid < 2) {
    int target = b + tid;
    int lo = 0, hi = NN;
    while (lo < hi) { int mid = (lo + hi) >> 1; if (batch[mid] < target) lo = mid + 1; else hi = mid; }
    rng[tid] = lo;
  }
  __syncthreads();
  const int s = rng[0], e = rng[1];
  if (tid < 45) {
    float acc = 0.f;
    for (int n = s; n < e; n++) acc += h3[n * 45 + tid];
    g[tid] = acc;
  }
  __syncthreads();
  if (tid < 90) {
    float acc = fc1_b[tid];
#pragma unroll 5
    for (int i = 0; i < 45; i++) acc = fmaf(g[i], fc1_w[i * 90 + tid], acc);
    go[tid] = fmaxf(acc, 0.f) * out_w[tid];
  }
  __syncthreads();
  if (tid == 0) {
    float acc = out_b[0];
    for (int i = 0; i < 90; i++) acc += go[i];
    out[b] = acc;
  }
}

extern "C" void kernel_launch(void* const* d_in, const int* in_sizes, int n_in,
                              void* d_out, int out_size, void* d_ws, size_t ws_size,
                              hipStream_t stream) {
  const float* x       = (const float*)d_in[0];
  const float* pos     = (const float*)d_in[1];
  const float* ea      = (const float*)d_in[2];
  const int*   eidx    = (const int*)d_in[3];
  const int*   batch   = (const int*)d_in[4];
  const float* c1_w1   = (const float*)d_in[5];
  const float* c1_b1   = (const float*)d_in[6];
  const float* c1_w2   = (const float*)d_in[7];
  const float* c1_b2   = (const float*)d_in[8];
  const float* c1_root = (const float*)d_in[9];
  const float* c1_bias = (const float*)d_in[10];
  const float* c2_w1   = (const float*)d_in[11];
  const float* c2_b1   = (const float*)d_in[12];
  const float* c2_w2   = (const float*)d_in[13];
  const float* c2_b2   = (const float*)d_in[14];
  const float* c2_root = (const float*)d_in[15];
  const float* c2_bias = (const float*)d_in[16];
  const float* c3_w1   = (const float*)d_in[17];
  const float* c3_b1   = (const float*)d_in[18];
  const float* c3_w2   = (const float*)d_in[19];
  const float* c3_b2   = (const float*)d_in[20];
  const float* c3_root = (const float*)d_in[21];
  const float* c3_bias = (const float*)d_in[22];
  const float* fc1_w   = (const float*)d_in[23];
  const float* fc1_b   = (const float*)d_in[24];
  const float* out_w   = (const float*)d_in[25];
  const float* out_b   = (const float*)d_in[26];
  const int* src = eidx;
  const int* dst = eidx + NE;

  // workspace carve
  float* ws  = (float*)d_ws;
  float* h0  = ws;                       // NN*16
  float* h1  = h0 + NN * 16;             // NN*90
  float* h2  = h1 + NN * 90;             // NN*90
  float* h3  = h2 + NN * 90;             // NN*45
  float* agg = h3 + NN * 45;             // NN*90
  unsigned short* he_bf = (unsigned short*)(agg + NN * 90);   // NE*96
  unsigned short* wp1 = he_bf + (size_t)NE * 96;              // 16*6*3*512
  unsigned short* wp2 = wp1 + (size_t)16 * 6 * 3 * 512;       // 90*6*3*512
  unsigned short* wp3 = wp2 + (size_t)90 * 6 * 3 * 512;       // 90*3*3*512

  concat_kernel<<<(NN * 16) / 256, 256, 0, stream>>>(x, pos, h0);

  wprep_frag<90, 6><<<16 * 3, 256, 0, stream>>>(c1_w2, c1_b2, wp1, 16 * 90);
  wprep_frag<90, 6><<<90 * 3, 256, 0, stream>>>(c2_w2, c2_b2, wp2, 90 * 90);
  wprep_frag<45, 3><<<90 * 3, 256, 0, stream>>>(c3_w2, c3_b2, wp3, 90 * 45);

  // conv1: 16 -> 90
  hipMemsetAsync(agg, 0, (size_t)NN * 90 * sizeof(float), stream);
  edge_mlp_bf<<<(NE * 96) / 256, 256, 0, stream>>>(ea, c1_w1, c1_b1, he_bf);
  msg_mfma<16, 90, 6, 2, 4><<<NE / 128, 256, 0, stream>>>(he_bf, h0, src, dst, wp1, agg);
  node_kernel<16, 90><<<(NN * 90) / 256, 256, 0, stream>>>(agg, h0, c1_root, c1_bias, h1);

  // conv2: 90 -> 90
  hipMemsetAsync(agg, 0, (size_t)NN * 90 * sizeof(float), stream);
  edge_mlp_bf<<<(NE * 96) / 256, 256, 0, stream>>>(ea, c2_w1, c2_b1, he_bf);
  msg_mfma<90, 90, 6, 2, 4><<<NE / 128, 256, 0, stream>>>(he_bf, h1, src, dst, wp2, agg);
  node_kernel<90, 90><<<(NN * 90) / 256, 256, 0, stream>>>(agg, h1, c2_root, c2_bias, h2);

  // conv3: 90 -> 45  (WNV=1: all 4 waves span the 3 o-tiles, WM=2 -> 128 edges)
  hipMemsetAsync(agg, 0, (size_t)NN * 45 * sizeof(float), stream);
  edge_mlp_bf<<<(NE * 96) / 256, 256, 0, stream>>>(ea, c3_w1, c3_b1, he_bf);
  msg_mfma<90, 45, 3, 1, 2><<<NE / 128, 256, 0, stream>>>(he_bf, h2, src, dst, wp3, agg);
  node_kernel<90, 45><<<(NN * 45 + 255) / 256, 256, 0, stream>>>(agg, h2, c3_root, c3_bias, h3);

  pool_mlp_kernel<<<NG, 128, 0, stream>>>(h3, batch, fc1_w, fc1_b, out_w, out_b, (float*)d_out);
}

// Round 7
// 573.362 us; speedup vs baseline: 1.5309x; 1.4408x over previous
//
#include <hip/hip_runtime.h>

#define NN 16000   // nodes
#define NE 64000   // edges
#define HD 90      // hidden
#define NG 512     // graphs

typedef float f32x4 __attribute__((ext_vector_type(4)));
typedef short s16x8 __attribute__((ext_vector_type(8)));

// round-half-up f32 -> bf16
__device__ __forceinline__ unsigned short rhu1(float f) {
  return (unsigned short)((__builtin_bit_cast(unsigned int, f) + 0x8000u) >> 16);
}
// pack two f32 -> bf16x2 (lo in low half), RHU rounding
__device__ __forceinline__ unsigned int rhu_pack(float lo, float hi) {
  unsigned int ul = __builtin_bit_cast(unsigned int, lo) + 0x8000u;
  unsigned int uh = __builtin_bit_cast(unsigned int, hi) + 0x8000u;
  return __builtin_amdgcn_perm(uh, ul, 0x07060302u);
}
__device__ __forceinline__ float bfhi(unsigned int u) {
  return __builtin_bit_cast(float, u & 0xFFFF0000u);
}
__device__ __forceinline__ float bflo(unsigned int u) {
  return __builtin_bit_cast(float, u << 16);
}

// h0 = concat(x, pos) : [NN, 16]
__global__ void concat_kernel(const float* __restrict__ x, const float* __restrict__ pos,
                              float* __restrict__ h0) {
  int idx = blockIdx.x * 256 + threadIdx.x;
  if (idx >= NN * 16) return;
  int n = idx >> 4, c = idx & 15;
  h0[idx] = (c < 13) ? x[n * 13 + c] : pos[n * 3 + (c - 13)];
}

// he_bf[e][k] : [NE, 96] bf16. k<90: relu(edge MLP); k==90: 1.0 (bias row); k>90: 0
__global__ void edge_mlp_bf(const float* __restrict__ ea, const float* __restrict__ w1,
                            const float* __restrict__ b1, unsigned short* __restrict__ he) {
  int idx = blockIdx.x * 256 + threadIdx.x;
  if (idx >= NE * 96) return;
  int e = idx / 96, k = idx - e * 96;
  unsigned short v;
  if (k < 90) {
    const float* a = ea + e * 8;
    float acc = b1[k];
#pragma unroll
    for (int j = 0; j < 8; j++) acc = fmaf(a[j], w1[j * HD + k], acc);
    v = rhu1(fmaxf(acc, 0.f));
  } else {
    v = (k == 90) ? (unsigned short)0x3F80 : (unsigned short)0;  // bf16(1.0) / 0
  }
  he[idx] = v;
}

// W' prep in MFMA-B-fragment order: shorts laid out as
//   [i][tile t(NTT)][chunk c(3)][lane(64)][j(8)]
// value(i,t,c,lane,j): hk=c*32+(lane>>4)*8+j, o=t*16+(lane&15);
//   hk<90 -> w2[hk][i*OC+o]; hk==90 -> b2[i*OC+o]; else 0.   One block per (i,c).
template <int OC, int NTT>
__global__ void wprep_frag(const float* __restrict__ w2, const float* __restrict__ b2,
                           unsigned short* __restrict__ wout, int inc_oc) {
  const int i = blockIdx.x / 3, c = blockIdx.x - 3 * (blockIdx.x / 3);
  __shared__ float t_s[32 * 100];
  const int tid = threadIdx.x;
  for (int idx = tid; idx < 32 * 96; idx += 256) {
    int kk = idx / 96, o = idx - kk * 96;
    int hk = c * 32 + kk;
    float v = 0.f;
    if (o < OC) {
      if (hk < 90) v = w2[hk * inc_oc + i * OC + o];        // coalesced along o
      else if (hk == 90) v = b2[i * OC + o];
    }
    t_s[kk * 100 + o] = v;
  }
  __syncthreads();
  unsigned int* wo = (unsigned int*)(wout + (size_t)i * NTT * 3 * 512) + c * 256;
  for (int idx = tid; idx < NTT * 256; idx += 256) {
    int t = idx >> 8, r = idx & 255;
    int lane = r >> 2, u = r & 3;
    int kk = (lane >> 4) * 8 + 2 * u;
    int o = t * 16 + (lane & 15);
    wo[(size_t)t * 3 * 256 + lane * 4 + u] = rhu_pack(t_s[kk * 100 + o], t_s[(kk + 1) * 100 + o]);
  }
}

// Fused message GEMM + scatter, i-outer, barrier-free K-loop, rolling W prefetch:
//   tmp_i[e][o] = sum_hk he[e][hk] * W'[i][hk][o]   (3 chained MFMAs; he in regs)
//   acc[e][o]  += z[e][i] * tmp_i[e][o]             (f32 fma; z bf16 from LDS)
// Per wave: 2 m-tiles x 3 n-tiles. W' frags single-buffered (9 regs x uint4);
// each tile's 3 slots reloaded for i+1 right after their MFMAs at iter i.
// EPB edges/block, NWG n-groups (NTT = NWG*3 tiles), WMG = EPB/32 m-pairs.
template <int ILIM, int OC, int NTT, int NWG, int EPB, int BLK>
__global__ __launch_bounds__(BLK, 2)
void msg_mfma(const unsigned short* __restrict__ he,
              const float* __restrict__ nin,
              const int* __restrict__ src, const int* __restrict__ dst,
              const unsigned short* __restrict__ wp,
              float* __restrict__ agg) {
  constexpr int WMG = EPB / 32;
  constexpr int TPE = BLK / EPB;
  __shared__ unsigned short zb[ILIM * WMG * 32];   // [i][wm][q][8] bf16, quad-permuted
  __shared__ int dst_s[EPB];
  const int tid = threadIdx.x;
  const int e0 = blockIdx.x * EPB;
  const int wid = tid >> 6, l = tid & 63, ln = tid & 15, q = (tid & 63) >> 4;
  const int wn = wid % NWG, wm = wid / NWG;
  const int eb = wm * 32;
  const int wn3 = wn * 3;

  if (tid < EPB) dst_s[tid] = dst[e0 + tid];

  // stage z (bf16) into quad-permuted layout:
  //   slot(e,i) = (i*WMG + (e>>5))*32 + ((e&15)>>2)*8 + ((e>>4)&1)*4 + (e&3)
  {
    const int e = tid % EPB, jj = tid / EPB;
    const int base = (e >> 5) * 32 + (((e & 15) >> 2) << 3) + (((e >> 4) & 1) << 2) + (e & 3);
    const float* zr = nin + (size_t)src[e0 + e] * ILIM;
    for (int p = jj; p < ILIM / 2; p += TPE) {
      const float2 v = *(const float2*)(zr + 2 * p);
      zb[(2 * p) * (WMG * 32) + base] = rhu1(v.x);
      zb[(2 * p + 1) * (WMG * 32) + base] = rhu1(v.y);
    }
  }

  // A-fragments: raw bf16 he, register-resident for the whole kernel
  s16x8 af[2][3];
#pragma unroll
  for (int mt = 0; mt < 2; mt++) {
    const unsigned short* hr = he + (size_t)(e0 + eb + mt * 16 + ln) * 96 + q * 8;
#pragma unroll
    for (int c = 0; c < 3; c++) af[mt][c] = *(const s16x8*)(hr + c * 32);
  }

  // W' fragment slots (single buffer, rolling reload); frag (i,T,c) at
  // shorts offset ((i*NTT + T)*3 + c)*512, T = wn3+ntl
  const unsigned short* wl = wp + l * 8;
  uint4 ba[9];
#pragma unroll
  for (int ntl = 0; ntl < 3; ntl++) {
    const unsigned short* wg = wl + (size_t)(wn3 + ntl) * 3 * 512;
#pragma unroll
    for (int c = 0; c < 3; c++) ba[ntl * 3 + c] = *(const uint4*)(wg + c * 512);
  }

  __syncthreads();   // zb/dst_s ready; no barriers after this

  f32x4 acc[2][3];
#pragma unroll
  for (int mt = 0; mt < 2; mt++)
#pragma unroll
    for (int nt = 0; nt < 3; nt++) acc[mt][nt] = (f32x4)0.f;

  for (int i = 0; i < ILIM; i++) {
    // z for this i: ONE b128 broadcast read -> 8 bf16 (4 rows mt0, 4 rows mt1)
    const uint4 zu = *(const uint4*)&zb[(i * WMG + wm) * 32 + q * 8];
    f32x4 zv0, zv1;
    zv0[0] = bflo(zu.x); zv0[1] = bfhi(zu.x); zv0[2] = bflo(zu.y); zv0[3] = bfhi(zu.y);
    zv1[0] = bflo(zu.z); zv1[1] = bfhi(zu.z); zv1[2] = bflo(zu.w); zv1[3] = bfhi(zu.w);
#pragma unroll
    for (int ntl = 0; ntl < 3; ntl++) {
      f32x4 t0 = __builtin_amdgcn_mfma_f32_16x16x32_bf16(af[0][0], __builtin_bit_cast(s16x8, ba[ntl * 3 + 0]), (f32x4)0.f, 0, 0, 0);
      t0 = __builtin_amdgcn_mfma_f32_16x16x32_bf16(af[0][1], __builtin_bit_cast(s16x8, ba[ntl * 3 + 1]), t0, 0, 0, 0);
      t0 = __builtin_amdgcn_mfma_f32_16x16x32_bf16(af[0][2], __builtin_bit_cast(s16x8, ba[ntl * 3 + 2]), t0, 0, 0, 0);
      f32x4 t1 = __builtin_amdgcn_mfma_f32_16x16x32_bf16(af[1][0], __builtin_bit_cast(s16x8, ba[ntl * 3 + 0]), (f32x4)0.f, 0, 0, 0);
      t1 = __builtin_amdgcn_mfma_f32_16x16x32_bf16(af[1][1], __builtin_bit_cast(s16x8, ba[ntl * 3 + 1]), t1, 0, 0, 0);
      t1 = __builtin_amdgcn_mfma_f32_16x16x32_bf16(af[1][2], __builtin_bit_cast(s16x8, ba[ntl * 3 + 2]), t1, 0, 0, 0);
      acc[0][ntl] += zv0 * t0;
      acc[1][ntl] += zv1 * t1;
      // rolling reload of this tile's 3 slots for i+1 (consumed next iter)
      if (i + 1 < ILIM) {
        const unsigned short* wg = wl + ((size_t)(i + 1) * NTT + wn3 + ntl) * 3 * 512;
        ba[ntl * 3 + 0] = *(const uint4*)(wg);
        ba[ntl * 3 + 1] = *(const uint4*)(wg + 512);
        ba[ntl * 3 + 2] = *(const uint4*)(wg + 1024);
      }
    }
  }

  // epilogue: D[row=q*4+r][col=ln] -> atomicAdd agg[dst]
#pragma unroll
  for (int mt = 0; mt < 2; mt++) {
#pragma unroll
    for (int ntl = 0; ntl < 3; ntl++) {
      int o = wn * 48 + ntl * 16 + ln;
      if (o < OC) {
#pragma unroll
        for (int r = 0; r < 4; r++) {
          int el = eb + mt * 16 + q * 4 + r;
          atomicAdd(agg + (size_t)dst_s[el] * OC + o, acc[mt][ntl][r]);
        }
      }
    }
  }
}

// out[n][o] = relu(agg[n][o] + sum_i nin[n][i]*root[i][o] + bias[o])   (fp32 exact)
template <int IN_C, int OC>
__global__ void node_kernel(const float* __restrict__ agg, const float* __restrict__ nin,
                            const float* __restrict__ root, const float* __restrict__ bias,
                            float* __restrict__ out) {
  int idx = blockIdx.x * 256 + threadIdx.x;
  if (idx >= NN * OC) return;
  int n = idx / OC, o = idx - n * OC;
  float acc = agg[idx] + bias[o];
  const float* inp = nin + (size_t)n * IN_C;
#pragma unroll 6
  for (int i = 0; i < IN_C; i++) acc = fmaf(inp[i], root[i * OC + o], acc);
  out[idx] = fmaxf(acc, 0.f);
}

// per-graph: pool (batch sorted -> binary search) + fc1 + out
__global__ void pool_mlp_kernel(const float* __restrict__ h3, const int* __restrict__ batch,
                                const float* __restrict__ fc1_w, const float* __restrict__ fc1_b,
                                const float* __restrict__ out_w, const float* __restrict__ out_b,
                                float* __restrict__ out) {
  const int b = blockIdx.x;
  const int tid = threadIdx.x;
  __shared__ float g[45];
  __shared__ float go[90];
  __shared__ int rng[2];
  if (tid < 2) {
    int target = b + tid;
    int lo = 0, hi = NN;
    while (lo < hi) { int mid = (lo + hi) >> 1; if (batch[mid] < target) lo = mid + 1; else hi = mid; }
    rng[tid] = lo;
  }
  __syncthreads();
  const int s = rng[0], e = rng[1];
  if (tid < 45) {
    float acc = 0.f;
    for (int n = s; n < e; n++) acc += h3[n * 45 + tid];
    g[tid] = acc;
  }
  __syncthreads();
  if (tid < 90) {
    float acc = fc1_b[tid];
#pragma unroll 5
    for (int i = 0; i < 45; i++) acc = fmaf(g[i], fc1_w[i * 90 + tid], acc);
    go[tid] = fmaxf(acc, 0.f) * out_w[tid];
  }
  __syncthreads();
  if (tid == 0) {
    float acc = out_b[0];
    for (int i = 0; i < 90; i++) acc += go[i];
    out[b] = acc;
  }
}

extern "C" void kernel_launch(void* const* d_in, const int* in_sizes, int n_in,
                              void* d_out, int out_size, void* d_ws, size_t ws_size,
                              hipStream_t stream) {
  const float* x       = (const float*)d_in[0];
  const float* pos     = (const float*)d_in[1];
  const float* ea      = (const float*)d_in[2];
  const int*   eidx    = (const int*)d_in[3];
  const int*   batch   = (const int*)d_in[4];
  const float* c1_w1   = (const float*)d_in[5];
  const float* c1_b1   = (const float*)d_in[6];
  const float* c1_w2   = (const float*)d_in[7];
  const float* c1_b2   = (const float*)d_in[8];
  const float* c1_root = (const float*)d_in[9];
  const float* c1_bias = (const float*)d_in[10];
  const float* c2_w1   = (const float*)d_in[11];
  const float* c2_b1   = (const float*)d_in[12];
  const float* c2_w2   = (const float*)d_in[13];
  const float* c2_b2   = (const float*)d_in[14];
  const float* c2_root = (const float*)d_in[15];
  const float* c2_bias = (const float*)d_in[16];
  const float* c3_w1   = (const float*)d_in[17];
  const float* c3_b1   = (const float*)d_in[18];
  const float* c3_w2   = (const float*)d_in[19];
  const float* c3_b2   = (const float*)d_in[20];
  const float* c3_root = (const float*)d_in[21];
  const float* c3_bias = (const float*)d_in[22];
  const float* fc1_w   = (const float*)d_in[23];
  const float* fc1_b   = (const float*)d_in[24];
  const float* out_w   = (const float*)d_in[25];
  const float* out_b   = (const float*)d_in[26];
  const int* src = eidx;
  const int* dst = eidx + NE;

  // workspace carve
  float* ws  = (float*)d_ws;
  float* h0  = ws;                       // NN*16
  float* h1  = h0 + NN * 16;             // NN*90
  float* h2  = h1 + NN * 90;             // NN*90
  float* h3  = h2 + NN * 90;             // NN*45
  float* agg = h3 + NN * 45;             // NN*90
  unsigned short* he_bf = (unsigned short*)(agg + NN * 90);   // NE*96
  unsigned short* wp1 = he_bf + (size_t)NE * 96;              // 16*6*3*512
  unsigned short* wp2 = wp1 + (size_t)16 * 6 * 3 * 512;       // 90*6*3*512
  unsigned short* wp3 = wp2 + (size_t)90 * 6 * 3 * 512;       // 90*3*3*512

  concat_kernel<<<(NN * 16) / 256, 256, 0, stream>>>(x, pos, h0);

  wprep_frag<90, 6><<<16 * 3, 256, 0, stream>>>(c1_w2, c1_b2, wp1, 16 * 90);
  wprep_frag<90, 6><<<90 * 3, 256, 0, stream>>>(c2_w2, c2_b2, wp2, 90 * 90);
  wprep_frag<45, 3><<<90 * 3, 256, 0, stream>>>(c3_w2, c3_b2, wp3, 90 * 45);

  // conv1: 16 -> 90   (64 edges/block, 4 waves: 2 m-pairs x 2 n-groups)
  hipMemsetAsync(agg, 0, (size_t)NN * 90 * sizeof(float), stream);
  edge_mlp_bf<<<(NE * 96) / 256, 256, 0, stream>>>(ea, c1_w1, c1_b1, he_bf);
  msg_mfma<16, 90, 6, 2, 64, 256><<<NE / 64, 256, 0, stream>>>(he_bf, h0, src, dst, wp1, agg);
  node_kernel<16, 90><<<(NN * 90) / 256, 256, 0, stream>>>(agg, h0, c1_root, c1_bias, h1);

  // conv2: 90 -> 90
  hipMemsetAsync(agg, 0, (size_t)NN * 90 * sizeof(float), stream);
  edge_mlp_bf<<<(NE * 96) / 256, 256, 0, stream>>>(ea, c2_w1, c2_b1, he_bf);
  msg_mfma<90, 90, 6, 2, 64, 256><<<NE / 64, 256, 0, stream>>>(he_bf, h1, src, dst, wp2, agg);
  node_kernel<90, 90><<<(NN * 90) / 256, 256, 0, stream>>>(agg, h1, c2_root, c2_bias, h2);

  // conv3: 90 -> 45   (128 edges/block, 4 waves: 4 m-pairs x 1 n-group)
  hipMemsetAsync(agg, 0, (size_t)NN * 45 * sizeof(float), stream);
  edge_mlp_bf<<<(NE * 96) / 256, 256, 0, stream>>>(ea, c3_w1, c3_b1, he_bf);
  msg_mfma<90, 45, 3, 1, 128, 256><<<NE / 128, 256, 0, stream>>>(he_bf, h2, src, dst, wp3, agg);
  node_kernel<90, 45><<<(NN * 45 + 255) / 256, 256, 0, stream>>>(agg, h2, c3_root, c3_bias, h3);

  pool_mlp_kernel<<<NG, 128, 0, stream>>>(h3, batch, fc1_w, fc1_b, out_w, out_b, (float*)d_out);
}

// Round 8
// 558.170 us; speedup vs baseline: 1.5726x; 1.0272x over previous
//
#include <hip/hip_runtime.h>

#define NN 16000   // nodes
#define NE 64000   // edges
#define HD 90      // hidden
#define NG 512     // graphs

typedef float f32x4 __attribute__((ext_vector_type(4)));
typedef short s16x8 __attribute__((ext_vector_type(8)));

// round-half-up f32 -> bf16
__device__ __forceinline__ unsigned short rhu1(float f) {
  return (unsigned short)((__builtin_bit_cast(unsigned int, f) + 0x8000u) >> 16);
}
// pack two f32 -> bf16x2 (lo in low half), RHU rounding
__device__ __forceinline__ unsigned int rhu_pack(float lo, float hi) {
  unsigned int ul = __builtin_bit_cast(unsigned int, lo) + 0x8000u;
  unsigned int uh = __builtin_bit_cast(unsigned int, hi) + 0x8000u;
  return __builtin_amdgcn_perm(uh, ul, 0x07060302u);
}
__device__ __forceinline__ float bfhi(unsigned int u) {
  return __builtin_bit_cast(float, u & 0xFFFF0000u);
}
__device__ __forceinline__ float bflo(unsigned int u) {
  return __builtin_bit_cast(float, u << 16);
}

// h0 = concat(x, pos) : [NN, 16]
__global__ void concat_kernel(const float* __restrict__ x, const float* __restrict__ pos,
                              float* __restrict__ h0) {
  int idx = blockIdx.x * 256 + threadIdx.x;
  if (idx >= NN * 16) return;
  int n = idx >> 4, c = idx & 15;
  h0[idx] = (c < 13) ? x[n * 13 + c] : pos[n * 3 + (c - 13)];
}

// he_bf[e][k] : [NE, 96] bf16. k<90: relu(edge MLP); k==90: 1.0 (bias row); k>90: 0
__global__ void edge_mlp_bf(const float* __restrict__ ea, const float* __restrict__ w1,
                            const float* __restrict__ b1, unsigned short* __restrict__ he) {
  int idx = blockIdx.x * 256 + threadIdx.x;
  if (idx >= NE * 96) return;
  int e = idx / 96, k = idx - e * 96;
  unsigned short v;
  if (k < 90) {
    const float* a = ea + e * 8;
    float acc = b1[k];
#pragma unroll
    for (int j = 0; j < 8; j++) acc = fmaf(a[j], w1[j * HD + k], acc);
    v = rhu1(fmaxf(acc, 0.f));
  } else {
    v = (k == 90) ? (unsigned short)0x3F80 : (unsigned short)0;  // bf16(1.0) / 0
  }
  he[idx] = v;
}

// W' prep in MFMA-B-fragment order: shorts laid out as
//   [i][tile t(NTT)][chunk c(3)][lane(64)][j(8)]
// value(i,t,c,lane,j): hk=c*32+(lane>>4)*8+j, o=t*16+(lane&15);
//   hk<90 -> w2[hk][i*OC+o]; hk==90 -> b2[i*OC+o]; else 0.   One block per (i,c).
template <int OC, int NTT>
__global__ void wprep_frag(const float* __restrict__ w2, const float* __restrict__ b2,
                           unsigned short* __restrict__ wout, int inc_oc) {
  const int i = blockIdx.x / 3, c = blockIdx.x - 3 * (blockIdx.x / 3);
  __shared__ float t_s[32 * 100];
  const int tid = threadIdx.x;
  for (int idx = tid; idx < 32 * 96; idx += 256) {
    int kk = idx / 96, o = idx - kk * 96;
    int hk = c * 32 + kk;
    float v = 0.f;
    if (o < OC) {
      if (hk < 90) v = w2[hk * inc_oc + i * OC + o];        // coalesced along o
      else if (hk == 90) v = b2[i * OC + o];
    }
    t_s[kk * 100 + o] = v;
  }
  __syncthreads();
  unsigned int* wo = (unsigned int*)(wout + (size_t)i * NTT * 3 * 512) + c * 256;
  for (int idx = tid; idx < NTT * 256; idx += 256) {
    int t = idx >> 8, r = idx & 255;
    int lane = r >> 2, u = r & 3;
    int kk = (lane >> 4) * 8 + 2 * u;
    int o = t * 16 + (lane & 15);
    wo[(size_t)t * 3 * 256 + lane * 4 + u] = rhu_pack(t_s[kk * 100 + o], t_s[(kk + 1) * 100 + o]);
  }
}

// Fused message GEMM + scatter, i-outer, barrier-free K-loop, rolling W prefetch:
//   tmp_i[e][o] = sum_hk he[e][hk] * W'[i][hk][o]   (3 chained MFMAs; he in regs)
//   acc[e][o]  += z[e][i] * tmp_i[e][o]             (f32 fma; z bf16 from LDS)
// Per wave: 2 m-tiles x 3 n-tiles. W' frags single-buffered (9 regs x uint4);
// each tile's 3 slots reloaded for i+1 right after their MFMAs at iter i.
// i-loop unroll DISABLED: full unroll at ILIM=16 (conv1) ballooned live
// prefetches -> 128 VGPR + 196 MB scratch spill (round-7 counters).
// launch_bounds(...,4): 4 waves/EU (VGPR<=128; round-7 usage 68) for latency hiding.
template <int ILIM, int OC, int NTT, int NWG, int EPB, int BLK>
__global__ __launch_bounds__(BLK, 4)
void msg_mfma(const unsigned short* __restrict__ he,
              const float* __restrict__ nin,
              const int* __restrict__ src, const int* __restrict__ dst,
              const unsigned short* __restrict__ wp,
              float* __restrict__ agg) {
  constexpr int WMG = EPB / 32;
  constexpr int TPE = BLK / EPB;
  __shared__ unsigned short zb[ILIM * WMG * 32];   // [i][wm][q][8] bf16, quad-permuted
  __shared__ int dst_s[EPB];
  const int tid = threadIdx.x;
  const int e0 = blockIdx.x * EPB;
  const int wid = tid >> 6, l = tid & 63, ln = tid & 15, q = (tid & 63) >> 4;
  const int wn = wid % NWG, wm = wid / NWG;
  const int eb = wm * 32;
  const int wn3 = wn * 3;

  if (tid < EPB) dst_s[tid] = dst[e0 + tid];

  // stage z (bf16) into quad-permuted layout:
  //   slot(e,i) = (i*WMG + (e>>5))*32 + ((e&15)>>2)*8 + ((e>>4)&1)*4 + (e&3)
  {
    const int e = tid % EPB, jj = tid / EPB;
    const int base = (e >> 5) * 32 + (((e & 15) >> 2) << 3) + (((e >> 4) & 1) << 2) + (e & 3);
    const float* zr = nin + (size_t)src[e0 + e] * ILIM;
    for (int p = jj; p < ILIM / 2; p += TPE) {
      const float2 v = *(const float2*)(zr + 2 * p);
      zb[(2 * p) * (WMG * 32) + base] = rhu1(v.x);
      zb[(2 * p + 1) * (WMG * 32) + base] = rhu1(v.y);
    }
  }

  // A-fragments: raw bf16 he, register-resident for the whole kernel
  s16x8 af[2][3];
#pragma unroll
  for (int mt = 0; mt < 2; mt++) {
    const unsigned short* hr = he + (size_t)(e0 + eb + mt * 16 + ln) * 96 + q * 8;
#pragma unroll
    for (int c = 0; c < 3; c++) af[mt][c] = *(const s16x8*)(hr + c * 32);
  }

  // W' fragment slots (single buffer, rolling reload); frag (i,T,c) at
  // shorts offset ((i*NTT + T)*3 + c)*512, T = wn3+ntl
  const unsigned short* wl = wp + l * 8;
  uint4 ba[9];
#pragma unroll
  for (int ntl = 0; ntl < 3; ntl++) {
    const unsigned short* wg = wl + (size_t)(wn3 + ntl) * 3 * 512;
#pragma unroll
    for (int c = 0; c < 3; c++) ba[ntl * 3 + c] = *(const uint4*)(wg + c * 512);
  }

  __syncthreads();   // zb/dst_s ready; no barriers after this

  f32x4 acc[2][3];
#pragma unroll
  for (int mt = 0; mt < 2; mt++)
#pragma unroll
    for (int nt = 0; nt < 3; nt++) acc[mt][nt] = (f32x4)0.f;

#pragma clang loop unroll(disable)
  for (int i = 0; i < ILIM; i++) {
    // z for this i: ONE b128 broadcast read -> 8 bf16 (4 rows mt0, 4 rows mt1)
    const uint4 zu = *(const uint4*)&zb[(i * WMG + wm) * 32 + q * 8];
    f32x4 zv0, zv1;
    zv0[0] = bflo(zu.x); zv0[1] = bfhi(zu.x); zv0[2] = bflo(zu.y); zv0[3] = bfhi(zu.y);
    zv1[0] = bflo(zu.z); zv1[1] = bfhi(zu.z); zv1[2] = bflo(zu.w); zv1[3] = bfhi(zu.w);
#pragma unroll
    for (int ntl = 0; ntl < 3; ntl++) {
      f32x4 t0 = __builtin_amdgcn_mfma_f32_16x16x32_bf16(af[0][0], __builtin_bit_cast(s16x8, ba[ntl * 3 + 0]), (f32x4)0.f, 0, 0, 0);
      t0 = __builtin_amdgcn_mfma_f32_16x16x32_bf16(af[0][1], __builtin_bit_cast(s16x8, ba[ntl * 3 + 1]), t0, 0, 0, 0);
      t0 = __builtin_amdgcn_mfma_f32_16x16x32_bf16(af[0][2], __builtin_bit_cast(s16x8, ba[ntl * 3 + 2]), t0, 0, 0, 0);
      f32x4 t1 = __builtin_amdgcn_mfma_f32_16x16x32_bf16(af[1][0], __builtin_bit_cast(s16x8, ba[ntl * 3 + 0]), (f32x4)0.f, 0, 0, 0);
      t1 = __builtin_amdgcn_mfma_f32_16x16x32_bf16(af[1][1], __builtin_bit_cast(s16x8, ba[ntl * 3 + 1]), t1, 0, 0, 0);
      t1 = __builtin_amdgcn_mfma_f32_16x16x32_bf16(af[1][2], __builtin_bit_cast(s16x8, ba[ntl * 3 + 2]), t1, 0, 0, 0);
      acc[0][ntl] += zv0 * t0;
      acc[1][ntl] += zv1 * t1;
      // rolling reload of this tile's 3 slots for i+1 (consumed next iter)
      if (i + 1 < ILIM) {
        const unsigned short* wg = wl + ((size_t)(i + 1) * NTT + wn3 + ntl) * 3 * 512;
        ba[ntl * 3 + 0] = *(const uint4*)(wg);
        ba[ntl * 3 + 1] = *(const uint4*)(wg + 512);
        ba[ntl * 3 + 2] = *(const uint4*)(wg + 1024);
      }
    }
  }

  // epilogue: D[row=q*4+r][col=ln] -> atomicAdd agg[dst]
#pragma unroll
  for (int mt = 0; mt < 2; mt++) {
#pragma unroll
    for (int ntl = 0; ntl < 3; ntl++) {
      int o = wn * 48 + ntl * 16 + ln;
      if (o < OC) {
#pragma unroll
        for (int r = 0; r < 4; r++) {
          int el = eb + mt * 16 + q * 4 + r;
          atomicAdd(agg + (size_t)dst_s[el] * OC + o, acc[mt][ntl][r]);
        }
      }
    }
  }
}

// out[n][o] = relu(agg[n][o] + sum_i nin[n][i]*root[i][o] + bias[o])   (fp32 exact)
template <int IN_C, int OC>
__global__ void node_kernel(const float* __restrict__ agg, const float* __restrict__ nin,
                            const float* __restrict__ root, const float* __restrict__ bias,
                            float* __restrict__ out) {
  int idx = blockIdx.x * 256 + threadIdx.x;
  if (idx >= NN * OC) return;
  int n = idx / OC, o = idx - n * OC;
  float acc = agg[idx] + bias[o];
  const float* inp = nin + (size_t)n * IN_C;
#pragma unroll 6
  for (int i = 0; i < IN_C; i++) acc = fmaf(inp[i], root[i * OC + o], acc);
  out[idx] = fmaxf(acc, 0.f);
}

// per-graph: pool (batch sorted -> binary search) + fc1 + out
__global__ void pool_mlp_kernel(const float* __restrict__ h3, const int* __restrict__ batch,
                                const float* __restrict__ fc1_w, const float* __restrict__ fc1_b,
                                const float* __restrict__ out_w, const float* __restrict__ out_b,
                                float* __restrict__ out) {
  const int b = blockIdx.x;
  const int tid = threadIdx.x;
  __shared__ float g[45];
  __shared__ float go[90];
  __shared__ int rng[2];
  if (tid < 2) {
    int target = b + tid;
    int lo = 0, hi = NN;
    while (lo < hi) { int mid = (lo + hi) >> 1; if (batch[mid] < target) lo = mid + 1; else hi = mid; }
    rng[tid] = lo;
  }
  __syncthreads();
  const int s = rng[0], e = rng[1];
  if (tid < 45) {
    float acc = 0.f;
    for (int n = s; n < e; n++) acc += h3[n * 45 + tid];
    g[tid] = acc;
  }
  __syncthreads();
  if (tid < 90) {
    float acc = fc1_b[tid];
#pragma unroll 5
    for (int i = 0; i < 45; i++) acc = fmaf(g[i], fc1_w[i * 90 + tid], acc);
    go[tid] = fmaxf(acc, 0.f) * out_w[tid];
  }
  __syncthreads();
  if (tid == 0) {
    float acc = out_b[0];
    for (int i = 0; i < 90; i++) acc += go[i];
    out[b] = acc;
  }
}

extern "C" void kernel_launch(void* const* d_in, const int* in_sizes, int n_in,
                              void* d_out, int out_size, void* d_ws, size_t ws_size,
                              hipStream_t stream) {
  const float* x       = (const float*)d_in[0];
  const float* pos     = (const float*)d_in[1];
  const float* ea      = (const float*)d_in[2];
  const int*   eidx    = (const int*)d_in[3];
  const int*   batch   = (const int*)d_in[4];
  const float* c1_w1   = (const float*)d_in[5];
  const float* c1_b1   = (const float*)d_in[6];
  const float* c1_w2   = (const float*)d_in[7];
  const float* c1_b2   = (const float*)d_in[8];
  const float* c1_root = (const float*)d_in[9];
  const float* c1_bias = (const float*)d_in[10];
  const float* c2_w1   = (const float*)d_in[11];
  const float* c2_b1   = (const float*)d_in[12];
  const float* c2_w2   = (const float*)d_in[13];
  const float* c2_b2   = (const float*)d_in[14];
  const float* c2_root = (const float*)d_in[15];
  const float* c2_bias = (const float*)d_in[16];
  const float* c3_w1   = (const float*)d_in[17];
  const float* c3_b1   = (const float*)d_in[18];
  const float* c3_w2   = (const float*)d_in[19];
  const float* c3_b2   = (const float*)d_in[20];
  const float* c3_root = (const float*)d_in[21];
  const float* c3_bias = (const float*)d_in[22];
  const float* fc1_w   = (const float*)d_in[23];
  const float* fc1_b   = (const float*)d_in[24];
  const float* out_w   = (const float*)d_in[25];
  const float* out_b   = (const float*)d_in[26];
  const int* src = eidx;
  const int* dst = eidx + NE;

  // workspace carve
  float* ws  = (float*)d_ws;
  float* h0  = ws;                       // NN*16
  float* h1  = h0 + NN * 16;             // NN*90
  float* h2  = h1 + NN * 90;             // NN*90
  float* h3  = h2 + NN * 90;             // NN*45
  float* agg = h3 + NN * 45;             // NN*90
  unsigned short* he_bf = (unsigned short*)(agg + NN * 90);   // NE*96
  unsigned short* wp1 = he_bf + (size_t)NE * 96;              // 16*6*3*512
  unsigned short* wp2 = wp1 + (size_t)16 * 6 * 3 * 512;       // 90*6*3*512
  unsigned short* wp3 = wp2 + (size_t)90 * 6 * 3 * 512;       // 90*3*3*512

  concat_kernel<<<(NN * 16) / 256, 256, 0, stream>>>(x, pos, h0);

  wprep_frag<90, 6><<<16 * 3, 256, 0, stream>>>(c1_w2, c1_b2, wp1, 16 * 90);
  wprep_frag<90, 6><<<90 * 3, 256, 0, stream>>>(c2_w2, c2_b2, wp2, 90 * 90);
  wprep_frag<45, 3><<<90 * 3, 256, 0, stream>>>(c3_w2, c3_b2, wp3, 90 * 45);

  // conv1: 16 -> 90   (64 edges/block, 4 waves: 2 m-pairs x 2 n-groups)
  hipMemsetAsync(agg, 0, (size_t)NN * 90 * sizeof(float), stream);
  edge_mlp_bf<<<(NE * 96) / 256, 256, 0, stream>>>(ea, c1_w1, c1_b1, he_bf);
  msg_mfma<16, 90, 6, 2, 64, 256><<<NE / 64, 256, 0, stream>>>(he_bf, h0, src, dst, wp1, agg);
  node_kernel<16, 90><<<(NN * 90) / 256, 256, 0, stream>>>(agg, h0, c1_root, c1_bias, h1);

  // conv2: 90 -> 90
  hipMemsetAsync(agg, 0, (size_t)NN * 90 * sizeof(float), stream);
  edge_mlp_bf<<<(NE * 96) / 256, 256, 0, stream>>>(ea, c2_w1, c2_b1, he_bf);
  msg_mfma<90, 90, 6, 2, 64, 256><<<NE / 64, 256, 0, stream>>>(he_bf, h1, src, dst, wp2, agg);
  node_kernel<90, 90><<<(NN * 90) / 256, 256, 0, stream>>>(agg, h1, c2_root, c2_bias, h2);

  // conv3: 90 -> 45   (128 edges/block, 4 waves: 4 m-pairs x 1 n-group)
  hipMemsetAsync(agg, 0, (size_t)NN * 45 * sizeof(float), stream);
  edge_mlp_bf<<<(NE * 96) / 256, 256, 0, stream>>>(ea, c3_w1, c3_b1, he_bf);
  msg_mfma<90, 45, 3, 1, 128, 256><<<NE / 128, 256, 0, stream>>>(he_bf, h2, src, dst, wp3, agg);
  node_kernel<90, 45><<<(NN * 45 + 255) / 256, 256, 0, stream>>>(agg, h2, c3_root, c3_bias, h3);

  pool_mlp_kernel<<<NG, 128, 0, stream>>>(h3, batch, fc1_w, fc1_b, out_w, out_b, (float*)d_out);
}